// Round 1
// 792.212 us; speedup vs baseline: 1.2038x; 1.2038x over previous
//
#include <hip/hip_runtime.h>
#include <stdint.h>
#include <math.h>

// ---------------------------------------------------------------------------
// Fused transformer block w/ linear attention, bf16 MFMA GEMMs
//   B=4, N=4096 (TOK=16384 tokens), C=1024, H=16, d=64, HIDDEN=4096
// R6: replace 128x128 2-barrier gemm_bt with the 256x256 8-phase template
//     (T1 XCD swizzle + T2 st_16x32 LDS swizzle via pre-swizzled global src +
//      T3/T4 8-phase counted vmcnt(6) + T5 setprio). 8 waves (2Mx4N), BK=64,
//     128KiB LDS double buffer, 16x16x32 bf16 MFMA, acc 8x4 frags/wave.
// Stage-slot ledger (per iteration, tiles t=2it in buf0, t+1 in buf1):
//   P1: Am1(t+1)->buf1   P2: Am0(t+2)->buf0  P3: Bn0(t+2)->buf0
//   P4: Bn1(t+2)->buf0 + vmcnt(6)            P5: Am1(t+2)->buf0
//   P6: Am0(t+3)->buf1   P7: Bn0(t+3)->buf1  P8: Bn1(t+3)->buf1 + vmcnt(6)
// Unit deaths: Am0,Bn0 after P1 (B0 frags retained in regs for P4), Bn1 after
// P2, Am1 after P3 => every stage lands in a dead region; vmcnt(6) at P4/P8
// retires exactly the whole next K-tile (3 units = 6 loads stay in flight).
// Workspace: unchanged (248.5 MiB), pkv/pks overlay abuf.
// ---------------------------------------------------------------------------

#define TOK   16384
#define CDIM  1024
#define NHEAD 16
#define HD    64
#define SEQ   4096
#define NBH   64
#define HID   4096

typedef unsigned short u16;
typedef __attribute__((ext_vector_type(8))) short bf16x8;
typedef __attribute__((ext_vector_type(4))) float f32x4;
typedef __attribute__((ext_vector_type(4))) unsigned short u16x4;

__device__ __forceinline__ u16 f2bf(float f) {
  union { float f; uint32_t u; } c; c.f = f;
  uint32_t u = c.u;
  return (u16)((u + 0x7fffu + ((u >> 16) & 1u)) >> 16);  // RNE
}
__device__ __forceinline__ float bf2f(u16 h) {
  union { uint32_t u; float f; } c; c.u = ((uint32_t)h) << 16;
  return c.f;
}
__device__ __forceinline__ float gelu_fast(float u) {
  float y = 1.5957691216f * (u + 0.044715f * u * u * u);
  return u * __builtin_amdgcn_rcpf(1.0f + __expf(-y));
}

typedef const __attribute__((address_space(1))) uint32_t* gas_t;
typedef __attribute__((address_space(3))) uint32_t* las_t;
__device__ __forceinline__ void gl_lds16(const u16* g, u16* l) {
  __builtin_amdgcn_global_load_lds((gas_t)g, (las_t)l, 16, 0, 0);
}

// ---------------- weight convert fp32 -> bf16 (vectorized) -----------------
__global__ __launch_bounds__(256) void cvt_kernel(const float* __restrict__ in,
                                                  u16* __restrict__ out, int n4) {
  int i = blockIdx.x * 256 + threadIdx.x;
  if (i < n4) {
    float4 v = ((const float4*)in)[i];
    u16x4 o;
    o.x = f2bf(v.x); o.y = f2bf(v.y); o.z = f2bf(v.z); o.w = f2bf(v.w);
    ((u16x4*)out)[i] = o;
  }
}

// ---------------- LayerNorm (row of 1024), fp32 in -> bf16 out -------------
__global__ __launch_bounds__(256) void ln_kernel(const float* __restrict__ xin,
                                                 const float* __restrict__ g,
                                                 const float* __restrict__ b,
                                                 u16* __restrict__ out) {
  int row = blockIdx.x;
  int t = threadIdx.x;
  const float4* xr = (const float4*)(xin + (size_t)row * CDIM);
  float4 v = xr[t];
  float s  = v.x + v.y + v.z + v.w;
  float s2 = v.x * v.x + v.y * v.y + v.z * v.z + v.w * v.w;
#pragma unroll
  for (int off = 32; off > 0; off >>= 1) {
    s  += __shfl_down(s, off);
    s2 += __shfl_down(s2, off);
  }
  __shared__ float as_[4], bs_[4];
  if ((t & 63) == 0) { as_[t >> 6] = s; bs_[t >> 6] = s2; }
  __syncthreads();
  s  = as_[0] + as_[1] + as_[2] + as_[3];
  s2 = bs_[0] + bs_[1] + bs_[2] + bs_[3];
  float mu  = s * (1.0f / CDIM);
  float var = s2 * (1.0f / CDIM) - mu * mu;
  float rs  = rsqrtf(var + 1e-5f);
  float4 gv = ((const float4*)g)[t];
  float4 bv = ((const float4*)b)[t];
  u16x4 o;
  o.x = f2bf((v.x - mu) * rs * gv.x + bv.x);
  o.y = f2bf((v.y - mu) * rs * gv.y + bv.y);
  o.z = f2bf((v.z - mu) * rs * gv.z + bv.z);
  o.w = f2bf((v.w - mu) * rs * gv.w + bv.w);
  ((u16x4*)(out + (size_t)row * CDIM))[t] = o;
}

// ---------------- main GEMM: A[M,K] x W[N,K]^T, fused epilogues ------------
enum { M_QKV = 0, M_PROJ = 1, M_FC1 = 2, M_FC2 = 3 };

#define BARRIER() do { asm volatile("" ::: "memory"); \
                       __builtin_amdgcn_s_barrier();  \
                       asm volatile("" ::: "memory"); } while (0)
#define WAITV(n)  asm volatile("s_waitcnt vmcnt(" #n ")" ::: "memory")

// register-subtile loads from swizzled LDS (c, mh/nh must be literals)
#define LDA(c, mh) do { \
  _Pragma("unroll") for (int mf = 0; mf < 4; ++mf) \
  _Pragma("unroll") for (int s = 0; s < 2; ++s) \
    a_[mf][s] = *(const bf16x8*)(ldsb + (c) * 65536 + abyte[mh][mf] + s * 64); \
} while (0)

#define LDB(c, nh, dst) do { \
  _Pragma("unroll") for (int nf = 0; nf < 2; ++nf) \
  _Pragma("unroll") for (int s = 0; s < 2; ++s) \
    dst[nf][s] = *(const bf16x8*)(ldsb + (c) * 65536 + 32768 + bbyte[nh][nf] + s * 64); \
} while (0)

// stage one 16KB unit (2 x global_load_lds / thread), inverse-swizzled source
#define STAGE_A(c, u, kt) do { \
  _Pragma("unroll") for (int i = 0; i < 2; ++i) \
    gl_lds16(Ab + aoff[i] + ((u) ? K64r : 0) + (size_t)(kt) * 64, \
             (u16*)(ldsb + (c) * 65536 + (u) * 16384 + pb[i])); \
} while (0)

#define STAGE_B(c, u, kt) do { \
  _Pragma("unroll") for (int i = 0; i < 2; ++i) \
    gl_lds16(Wb + boff[i] + ((u) ? K32r : 0) + (size_t)(kt) * 64, \
             (u16*)(ldsb + (c) * 65536 + 32768 + (u) * 16384 + pb[i])); \
} while (0)

// one C-quadrant: 16 MFMA, setprio-wrapped (T5)
#define MFMA16(mo, no, B) do { \
  __builtin_amdgcn_s_setprio(1); \
  _Pragma("unroll") for (int s = 0; s < 2; ++s) \
  _Pragma("unroll") for (int mf = 0; mf < 4; ++mf) \
  _Pragma("unroll") for (int nf = 0; nf < 2; ++nf) \
    acc[(mo) + mf][(no) + nf] = __builtin_amdgcn_mfma_f32_16x16x32_bf16( \
        a_[mf][s], B[nf][s], acc[(mo) + mf][(no) + nf], 0, 0, 0); \
  __builtin_amdgcn_s_setprio(0); \
} while (0)

template <int MODE>
__global__ __launch_bounds__(512, 2) void gemm256(const u16* __restrict__ A,
                                                  const u16* __restrict__ W, int K,
                                                  void* __restrict__ o0,
                                                  void* __restrict__ o1,
                                                  void* __restrict__ o2,
                                                  const float* __restrict__ bias,
                                                  const float* __restrict__ resid) {
  __shared__ __align__(16) u16 lds_[65536];  // 128 KiB: 2 bufs x (A 32K + B 32K)
  char* ldsb = (char*)lds_;
  const int t = threadIdx.x;
  const int l = t & 63, w = t >> 6;
  const int wm = w >> 2, wn = w & 3;            // 2 x 4 wave grid
  const int fr = l & 15, qq = l >> 4;           // 16x16 frag: row=fr, k-octet=qq

  // XCD-aware bijective swizzle (nwg % 8 == 0 for all our launches)
  const int nwg = gridDim.x;
  const int wg  = blockIdx.x;
  const int swz = (wg & 7) * (nwg >> 3) + (wg >> 3);
  const int mt = swz & 63, nt = swz >> 6;       // nmt = 16384/256 = 64 always
  const int m0 = mt * 256, n0 = nt * 256;

  const u16* Ab = A + (size_t)m0 * K;
  const u16* Wb = W + (size_t)n0 * K;
  const size_t K64r = (size_t)K * 64;           // 64 A-rows
  const size_t K32r = (size_t)K * 32;           // 32 B-rows

  // --- staging precompute: linear LDS dest p, inverse-st_16x32 source ---
  // physical p holds logical q = p ^ (((p>>9)&1)<<5); q = prow*128 + cbyte.
  // A unit u: row R = u*64 + (prow>>6)*128 + (prow&63)  (units: (R>>6)&1)
  // B unit u: row R = (prow>>5)*64 + u*32 + (prow&31)   (units: (R>>5)&1)
  size_t aoff[2], boff[2];
  int pb[2];
#pragma unroll
  for (int i = 0; i < 2; ++i) {
    int p = (i * 512 + t) * 16;
    int q = p ^ (((p >> 9) & 1) << 5);
    int prow = q >> 7;
    int kc = (q & 127) >> 1;
    pb[i] = p;
    aoff[i] = (size_t)(((prow >> 6) & 1) * 128 + (prow & 63)) * K + kc;
    boff[i] = (size_t)(((prow >> 5) & 3) * 64 + (prow & 31)) * K + kc;
  }
  // --- read-address precompute (swizzled): byte = slot*128 + qx*16 (+s*64) ---
  int abyte[2][4], bbyte[2][2];
#pragma unroll
  for (int mh = 0; mh < 2; ++mh)
#pragma unroll
    for (int mf = 0; mf < 4; ++mf) {
      int R = wm * 128 + (mh * 4 + mf) * 16 + fr;
      int slot = ((R >> 6) & 1) * 128 + ((R >> 7) & 1) * 64 + (R & 63);
      int qx = qq ^ (((slot >> 2) & 1) << 1);   // st_16x32: XOR byte bit5 w/ bit9
      abyte[mh][mf] = slot * 128 + qx * 16;
    }
#pragma unroll
  for (int nh = 0; nh < 2; ++nh)
#pragma unroll
    for (int nf = 0; nf < 2; ++nf) {
      int R = wn * 64 + (nh * 2 + nf) * 16 + fr;
      int slot = ((R >> 5) & 1) * 128 + ((R >> 6) & 3) * 32 + (R & 31);
      int qx = qq ^ (((slot >> 2) & 1) << 1);
      bbyte[nh][nf] = slot * 128 + qx * 16;
    }

  f32x4 acc[8][4] = {};
  bf16x8 a_[4][2], b0_[2][2], b1_[2][2];

  const int nkt = K >> 6;        // K-tiles of 64
  const int niter = nkt >> 1;    // 2 K-tiles per iteration (>= 8 for all modes)

  // prologue: tile0 complete + tile1 {Am0,Bn0,Bn1}; Am1(1) staged at P1 below
  STAGE_A(0, 0, 0); STAGE_B(0, 0, 0); STAGE_B(0, 1, 0); STAGE_A(0, 1, 0);
  STAGE_A(1, 0, 1); STAGE_B(1, 0, 1); STAGE_B(1, 1, 1);
  WAITV(6);
  BARRIER();

  for (int it = 0; it < niter - 1; ++it) {
    const int t0 = 2 * it;
    // P1: quad(m0,n0) of t0
    LDA(0, 0); LDB(0, 0, b0_);
    STAGE_A(1, 1, t0 + 1);
    BARRIER(); MFMA16(0, 0, b0_); BARRIER();
    // P2: quad(m0,n1)
    LDB(0, 1, b1_);
    STAGE_A(0, 0, t0 + 2);
    BARRIER(); MFMA16(0, 2, b1_); BARRIER();
    // P3: quad(m1,n1)
    LDA(0, 1);
    STAGE_B(0, 0, t0 + 2);
    BARRIER(); MFMA16(4, 2, b1_); BARRIER();
    // P4: quad(m1,n0) -- b0_ retained from P1
    STAGE_B(0, 1, t0 + 2);
    WAITV(6);
    BARRIER(); MFMA16(4, 0, b0_); BARRIER();
    // P5: quad(m0,n0) of t0+1
    LDA(1, 0); LDB(1, 0, b0_);
    STAGE_A(0, 1, t0 + 2);
    BARRIER(); MFMA16(0, 0, b0_); BARRIER();
    // P6: quad(m0,n1)
    LDB(1, 1, b1_);
    STAGE_A(1, 0, t0 + 3);
    BARRIER(); MFMA16(0, 2, b1_); BARRIER();
    // P7: quad(m1,n1)
    LDA(1, 1);
    STAGE_B(1, 0, t0 + 3);
    BARRIER(); MFMA16(4, 2, b1_); BARRIER();
    // P8: quad(m1,n0)
    STAGE_B(1, 1, t0 + 3);
    WAITV(6);
    BARRIER(); MFMA16(4, 0, b0_); BARRIER();
  }
  // peeled last iteration (tiles nkt-2, nkt-1); only Am1(nkt-1) left to stage
  {
    LDA(0, 0); LDB(0, 0, b0_);
    STAGE_A(1, 1, nkt - 1);
    BARRIER(); MFMA16(0, 0, b0_); BARRIER();
    LDB(0, 1, b1_);
    BARRIER(); MFMA16(0, 2, b1_); BARRIER();
    LDA(0, 1);
    BARRIER(); MFMA16(4, 2, b1_); BARRIER();
    WAITV(0);
    BARRIER(); MFMA16(4, 0, b0_); BARRIER();
    LDA(1, 0); LDB(1, 0, b0_);
    BARRIER(); MFMA16(0, 0, b0_); BARRIER();
    LDB(1, 1, b1_);
    BARRIER(); MFMA16(0, 2, b1_); BARRIER();
    LDA(1, 1);
    BARRIER(); MFMA16(4, 2, b1_); BARRIER();
    MFMA16(4, 0, b0_);
  }

  // epilogue: D element col = lane&15, row = qq*4 + r
#pragma unroll
  for (int mi = 0; mi < 8; ++mi) {
#pragma unroll
    for (int nj = 0; nj < 4; ++nj) {
      int go = n0 + wn * 64 + nj * 16 + fr;
#pragma unroll
      for (int r = 0; r < 4; ++r) {
        int gm = m0 + wm * 128 + mi * 16 + qq * 4 + r;
        float v = acc[mi][nj][r];
        if constexpr (MODE == M_QKV) {
          int sect = go >> 10, c = go & 1023;
          int h = c >> 6, dd = c & 63;
          int b = gm >> 12, n = gm & 4095;
          int bh = b * NHEAD + h;
          if (sect == 0) {          // q = elu(v)+1, layout [bh][n][d]
            float qv = v > 0.f ? v + 1.f : __expf(v);
            ((u16*)o0)[((size_t)bh * SEQ + n) * HD + dd] = f2bf(qv);
          } else if (sect == 1) {   // k = elu(v)+1, transposed [bh][d][n]
            float kk = v > 0.f ? v + 1.f : __expf(v);
            ((u16*)o1)[((size_t)bh * HD + dd) * SEQ + n] = f2bf(kk);
          } else {                  // v, transposed [bh][d][n]
            ((u16*)o2)[((size_t)bh * HD + dd) * SEQ + n] = f2bf(v);
          }
        } else if constexpr (MODE == M_PROJ) {
          ((float*)o0)[(size_t)gm * CDIM + go] = v + bias[go] + resid[(size_t)gm * CDIM + go];
        } else if constexpr (MODE == M_FC1) {
          float u = v + bias[go];
          ((u16*)o0)[(size_t)gm * HID + go] = f2bf(gelu_fast(u));
        } else {  // M_FC2
          ((float*)o0)[(size_t)gm * CDIM + go] = v + bias[go] + resid[(size_t)gm * CDIM + go];
        }
      }
    }
  }
}

// ------- kv state: partial kvT[e][d] = sum_n v[n,e]*k[n,d], per n-chunk -----
__global__ __launch_bounds__(256) void kv_stage1(const u16* __restrict__ kt,
                                                 const u16* __restrict__ vt,
                                                 float* __restrict__ pkv,
                                                 float* __restrict__ pks) {
  int ch = blockIdx.x, bh = blockIdx.y;
  int t = threadIdx.x, l = t & 63, w = t >> 6;
  int fr = l & 15, qq = l >> 4;
  int nb = ch * 512;
  const u16* vb = vt + (size_t)bh * HD * SEQ;
  const u16* kb = kt + (size_t)bh * HD * SEQ;
  int e0 = (w >> 1) * 32, d0 = (w & 1) * 32;
  f32x4 acc[2][2] = {};
  for (int kk = 0; kk < 512; kk += 32) {
    bf16x8 af[2], bfv[2];
#pragma unroll
    for (int i = 0; i < 2; ++i)
      af[i] = *(const bf16x8*)(vb + (size_t)(e0 + i * 16 + fr) * SEQ + nb + kk + qq * 8);
#pragma unroll
    for (int j = 0; j < 2; ++j)
      bfv[j] = *(const bf16x8*)(kb + (size_t)(d0 + j * 16 + fr) * SEQ + nb + kk + qq * 8);
#pragma unroll
    for (int i = 0; i < 2; ++i)
#pragma unroll
      for (int j = 0; j < 2; ++j)
        acc[i][j] = __builtin_amdgcn_mfma_f32_16x16x32_bf16(af[i], bfv[j], acc[i][j], 0, 0, 0);
  }
  float* pout = pkv + ((size_t)ch * NBH + bh) * 4096;
#pragma unroll
  for (int i = 0; i < 2; ++i)
#pragma unroll
    for (int j = 0; j < 2; ++j)
#pragma unroll
      for (int r = 0; r < 4; ++r) {
        int e = e0 + i * 16 + qq * 4 + r;
        int d = d0 + j * 16 + fr;
        pout[e * 64 + d] = acc[i][j][r];
      }
  // partial ksum over this n-chunk
  __shared__ float ksp[256];
  {
    int d = t & 63, part = t >> 6;
    const u16* kr = kb + (size_t)d * SEQ + nb + part * 128;
    float s = 0;
    for (int n = 0; n < 128; ++n) s += bf2f(kr[n]);
    ksp[t] = s;
  }
  __syncthreads();
  if (t < 64) {
    float s = ksp[t] + ksp[64 + t] + ksp[128 + t] + ksp[192 + t];
    pks[((size_t)ch * NBH + bh) * 64 + t] = s;
  }
}

__global__ __launch_bounds__(256) void kv_reduce(const float* __restrict__ pkv,
                                                 const float* __restrict__ pks,
                                                 u16* __restrict__ kvt,
                                                 float* __restrict__ ksm) {
  int bh = blockIdx.x, t = threadIdx.x;
  for (int ii = 0; ii < 16; ++ii) {
    int idx = ii * 256 + t;
    float s = 0;
#pragma unroll
    for (int c = 0; c < 8; ++c) s += pkv[((size_t)c * NBH + bh) * 4096 + idx];
    kvt[(size_t)bh * 4096 + idx] = f2bf(s);
  }
  if (t < 64) {
    float s = 0;
#pragma unroll
    for (int c = 0; c < 8; ++c) s += pks[((size_t)c * NBH + bh) * 64 + t];
    ksm[bh * 64 + t] = s;
  }
}

// ------- attn: out[n,e] = (sum_d q[n,d]*kvT[e,d]) * z[n], -> [b,n,c] bf16 ---
__global__ __launch_bounds__(256) void attn_kernel(const u16* __restrict__ qb,
                                                   const u16* __restrict__ kvt,
                                                   const float* __restrict__ ksm,
                                                   u16* __restrict__ ab) {
  int nblk = blockIdx.x, bh = blockIdx.y;
  int n0 = nblk * 128;
  int t = threadIdx.x, l = t & 63, w = t >> 6;
  int fr = l & 15, qq = l >> 4;
  __shared__ float ksh[64];
  __shared__ float part[256];
  __shared__ float zsh[128];
  if (t < 64) ksh[t] = ksm[bh * 64 + t];
  __syncthreads();
  {
    int rr = t >> 1, hf = t & 1;
    const u16* qr = qb + ((size_t)bh * SEQ + n0 + rr) * HD + hf * 32;
    float s = 0;
#pragma unroll
    for (int d = 0; d < 32; ++d) s += bf2f(qr[d]) * ksh[hf * 32 + d];
    part[t] = s;
  }
  __syncthreads();
  if (t < 128) zsh[t] = 1.0f / (part[2 * t] + part[2 * t + 1] + 1e-6f);
  __syncthreads();

  f32x4 acc[2][4] = {};
  const u16* qbase = qb + ((size_t)bh * SEQ + n0) * HD;
  const u16* kvb = kvt + (size_t)bh * 4096;
#pragma unroll
  for (int ks = 0; ks < 64; ks += 32) {
    bf16x8 af[2], bfv[4];
#pragma unroll
    for (int i = 0; i < 2; ++i)
      af[i] = *(const bf16x8*)(qbase + (size_t)(w * 32 + i * 16 + fr) * HD + ks + qq * 8);
#pragma unroll
    for (int j = 0; j < 4; ++j)
      bfv[j] = *(const bf16x8*)(kvb + (size_t)(j * 16 + fr) * HD + ks + qq * 8);
#pragma unroll
    for (int i = 0; i < 2; ++i)
#pragma unroll
      for (int j = 0; j < 4; ++j)
        acc[i][j] = __builtin_amdgcn_mfma_f32_16x16x32_bf16(af[i], bfv[j], acc[i][j], 0, 0, 0);
  }
  int b = bh >> 4, h = bh & 15;
#pragma unroll
  for (int i = 0; i < 2; ++i)
#pragma unroll
    for (int j = 0; j < 4; ++j)
#pragma unroll
      for (int r = 0; r < 4; ++r) {
        int rl = w * 32 + i * 16 + qq * 4 + r;
        int n = n0 + rl;
        int e = j * 16 + fr;
        float v = acc[i][j][r] * zsh[rl];
        ab[((size_t)(b * SEQ + n)) * CDIM + h * HD + e] = f2bf(v);
      }
}

// ---------------------------------------------------------------------------
extern "C" void kernel_launch(void* const* d_in, const int* in_sizes, int n_in,
                              void* d_out, int out_size, void* d_ws, size_t ws_size,
                              hipStream_t stream) {
  (void)in_sizes; (void)n_in; (void)out_size; (void)ws_size;
  const float* x     = (const float*)d_in[0];
  const float* n1g   = (const float*)d_in[1];
  const float* n1b   = (const float*)d_in[2];
  const float* qkvw  = (const float*)d_in[3];
  const float* projw = (const float*)d_in[4];
  const float* projb = (const float*)d_in[5];
  const float* n2g   = (const float*)d_in[6];
  const float* n2b   = (const float*)d_in[7];
  const float* fc1w  = (const float*)d_in[8];
  const float* fc1b  = (const float*)d_in[9];
  const float* fc2w  = (const float*)d_in[10];
  const float* fc2b  = (const float*)d_in[11];
  float* out = (float*)d_out;

  char* ws = (char*)d_ws;
  size_t off = 0;
  auto alloc = [&](size_t bytes) {
    void* p = ws + off;
    off += (bytes + 255) & ~(size_t)255;
    return p;
  };
  // --- persistent-lifetime allocations (248.5 MiB total incl. pool) ---
  u16*  wq   = (u16*)alloc((size_t)3 * CDIM * CDIM * 2);   // 6 MB  qkv_w bf16
  u16*  wp   = (u16*)alloc((size_t)CDIM * CDIM * 2);       // 2 MB  proj_w bf16
  u16*  w1   = (u16*)alloc((size_t)HID * CDIM * 2);        // 8 MB  fc1_w bf16
  u16*  w2   = (u16*)alloc((size_t)CDIM * HID * 2);        // 8 MB  fc2_w bf16
  u16*  kvt  = (u16*)alloc((size_t)NBH * 4096 * 2);        // 512KB kvT bf16
  float* ksm = (float*)alloc((size_t)NBH * 64 * 4);        // 16 KB ksum
  float* x2  = (float*)alloc((size_t)TOK * CDIM * 4);      // 64 MB x + attn (fp32)
  u16*  h12  = (u16*)alloc((size_t)TOK * CDIM * 2);        // 32 MB ln1 out, later ln2 out
  // --- 128 MB pool with overlaid lifetimes ---
  u16*  qbuf = (u16*)alloc((size_t)TOK * CDIM * 2);        // 32 MB phi(q) [bh][n][d]
  u16*  ktb  = (u16*)alloc((size_t)TOK * CDIM * 2);        // 32 MB phi(k) [bh][d][n]
  u16*  vtb  = (u16*)alloc((size_t)TOK * CDIM * 2);        // 32 MB v      [bh][d][n]
  u16*  abuf = (u16*)alloc((size_t)TOK * CDIM * 2);        // 32 MB attn out [b,n,c]
  // pkv/pks overlay abuf: dead before attn_kernel writes abuf
  float* pkv = (float*)abuf;                               // 8 MB  partial kv
  float* pks = (float*)(abuf + (size_t)8 * NBH * 4096 * 2);// 128KB partial ksum
  u16*  h3   = qbuf;  // 128 MB gelu out: reuses qbuf..abuf (all dead after proj)

  // weights fp32 -> bf16
  cvt_kernel<<<dim3(3 * CDIM * CDIM / 1024), 256, 0, stream>>>(qkvw, wq, 3 * CDIM * CDIM / 4);
  cvt_kernel<<<dim3(CDIM * CDIM / 1024),     256, 0, stream>>>(projw, wp, CDIM * CDIM / 4);
  cvt_kernel<<<dim3(HID * CDIM / 1024),      256, 0, stream>>>(fc1w, w1, HID * CDIM / 4);
  cvt_kernel<<<dim3(CDIM * HID / 1024),      256, 0, stream>>>(fc2w, w2, CDIM * HID / 4);

  ln_kernel<<<dim3(TOK), 256, 0, stream>>>(x, n1g, n1b, h12);
  gemm256<M_QKV><<<dim3(64 * 12), 512, 0, stream>>>(
      h12, wq, CDIM, qbuf, ktb, vtb, nullptr, nullptr);
  kv_stage1<<<dim3(8, NBH), 256, 0, stream>>>(ktb, vtb, pkv, pks);
  kv_reduce<<<dim3(NBH), 256, 0, stream>>>(pkv, pks, kvt, ksm);
  attn_kernel<<<dim3(SEQ / 128, NBH), 256, 0, stream>>>(qbuf, kvt, ksm, abuf);
  gemm256<M_PROJ><<<dim3(64 * 4), 512, 0, stream>>>(
      abuf, wp, CDIM, x2, nullptr, nullptr, projb, x);
  ln_kernel<<<dim3(TOK), 256, 0, stream>>>(x2, n2g, n2b, h12);
  gemm256<M_FC1><<<dim3(64 * 16), 512, 0, stream>>>(
      h12, w1, CDIM, h3, nullptr, nullptr, fc1b, nullptr);
  gemm256<M_FC2><<<dim3(64 * 4), 512, 0, stream>>>(
      h3, w2, HID, out, nullptr, nullptr, fc2b, x2);
}

// Round 2
// 684.926 us; speedup vs baseline: 1.3924x; 1.1566x over previous
//
#include <hip/hip_runtime.h>
#include <stdint.h>
#include <math.h>

// ---------------------------------------------------------------------------
// Fused transformer block w/ linear attention, bf16 MFMA GEMMs
//   B=4, N=4096 (TOK=16384 tokens), C=1024, H=16, d=64, HIDDEN=4096
// R7: 8-phase 256x256 template kept; three fixes on top of R6:
//  (1) 3-bit slot swizzle (byte ^= ((row&7)<<4)) replacing 1-bit st_16x32:
//      R6 measured exactly 3.0 conflict-cyc/ds_read (64 lanes -> only 4
//      16B slots = half the banks). 3-bit XOR spreads a 16-row fragment
//      across all 8 slots = all 32 banks. Read addr = base ^ (s<<6).
//  (2) XCD mapping: mt-band per XCD (8 A-panels = 4MB, L2-resident),
//      nt-major order (B panel fetched once per XCD by 8 consecutive wgs).
//      A-reads (512MB/dispatch at FC1) move from L3 to L2 pace.
//  (3) QKV k/v stores vectorized u16x4 (r-index = 4 consecutive n in
//      [bh][d][n] layout) -> 16x fewer write transactions on 64MB.
// Stage-slot ledger unchanged: vmcnt(6) at P4/P8 retires exactly one K-tile.
// ---------------------------------------------------------------------------

#define TOK   16384
#define CDIM  1024
#define NHEAD 16
#define HD    64
#define SEQ   4096
#define NBH   64
#define HID   4096

typedef unsigned short u16;
typedef __attribute__((ext_vector_type(8))) short bf16x8;
typedef __attribute__((ext_vector_type(4))) float f32x4;
typedef __attribute__((ext_vector_type(4))) unsigned short u16x4;

__device__ __forceinline__ u16 f2bf(float f) {
  union { float f; uint32_t u; } c; c.f = f;
  uint32_t u = c.u;
  return (u16)((u + 0x7fffu + ((u >> 16) & 1u)) >> 16);  // RNE
}
__device__ __forceinline__ float bf2f(u16 h) {
  union { uint32_t u; float f; } c; c.u = ((uint32_t)h) << 16;
  return c.f;
}
__device__ __forceinline__ float gelu_fast(float u) {
  float y = 1.5957691216f * (u + 0.044715f * u * u * u);
  return u * __builtin_amdgcn_rcpf(1.0f + __expf(-y));
}

typedef const __attribute__((address_space(1))) uint32_t* gas_t;
typedef __attribute__((address_space(3))) uint32_t* las_t;
__device__ __forceinline__ void gl_lds16(const u16* g, u16* l) {
  __builtin_amdgcn_global_load_lds((gas_t)g, (las_t)l, 16, 0, 0);
}

// ---------------- weight convert fp32 -> bf16 (vectorized) -----------------
__global__ __launch_bounds__(256) void cvt_kernel(const float* __restrict__ in,
                                                  u16* __restrict__ out, int n4) {
  int i = blockIdx.x * 256 + threadIdx.x;
  if (i < n4) {
    float4 v = ((const float4*)in)[i];
    u16x4 o;
    o.x = f2bf(v.x); o.y = f2bf(v.y); o.z = f2bf(v.z); o.w = f2bf(v.w);
    ((u16x4*)out)[i] = o;
  }
}

// ---------------- LayerNorm (row of 1024), fp32 in -> bf16 out -------------
__global__ __launch_bounds__(256) void ln_kernel(const float* __restrict__ xin,
                                                 const float* __restrict__ g,
                                                 const float* __restrict__ b,
                                                 u16* __restrict__ out) {
  int row = blockIdx.x;
  int t = threadIdx.x;
  const float4* xr = (const float4*)(xin + (size_t)row * CDIM);
  float4 v = xr[t];
  float s  = v.x + v.y + v.z + v.w;
  float s2 = v.x * v.x + v.y * v.y + v.z * v.z + v.w * v.w;
#pragma unroll
  for (int off = 32; off > 0; off >>= 1) {
    s  += __shfl_down(s, off);
    s2 += __shfl_down(s2, off);
  }
  __shared__ float as_[4], bs_[4];
  if ((t & 63) == 0) { as_[t >> 6] = s; bs_[t >> 6] = s2; }
  __syncthreads();
  s  = as_[0] + as_[1] + as_[2] + as_[3];
  s2 = bs_[0] + bs_[1] + bs_[2] + bs_[3];
  float mu  = s * (1.0f / CDIM);
  float var = s2 * (1.0f / CDIM) - mu * mu;
  float rs  = rsqrtf(var + 1e-5f);
  float4 gv = ((const float4*)g)[t];
  float4 bv = ((const float4*)b)[t];
  u16x4 o;
  o.x = f2bf((v.x - mu) * rs * gv.x + bv.x);
  o.y = f2bf((v.y - mu) * rs * gv.y + bv.y);
  o.z = f2bf((v.z - mu) * rs * gv.z + bv.z);
  o.w = f2bf((v.w - mu) * rs * gv.w + bv.w);
  ((u16x4*)(out + (size_t)row * CDIM))[t] = o;
}

// ---------------- main GEMM: A[M,K] x W[N,K]^T, fused epilogues ------------
enum { M_QKV = 0, M_PROJ = 1, M_FC1 = 2, M_FC2 = 3 };

#define BARRIER() do { asm volatile("" ::: "memory"); \
                       __builtin_amdgcn_s_barrier();  \
                       asm volatile("" ::: "memory"); } while (0)
#define WAITV(n)  asm volatile("s_waitcnt vmcnt(" #n ")" ::: "memory")

// register-subtile loads from swizzled LDS; s-half toggles addr bit 6
#define LDA(c, mh) do { \
  _Pragma("unroll") for (int mf = 0; mf < 4; ++mf) \
  _Pragma("unroll") for (int s = 0; s < 2; ++s) \
    a_[mf][s] = *(const bf16x8*)(ldsb + (c) * 65536 + (abyte[mh][mf] ^ (s * 64))); \
} while (0)

#define LDB(c, nh, dst) do { \
  _Pragma("unroll") for (int nf = 0; nf < 2; ++nf) \
  _Pragma("unroll") for (int s = 0; s < 2; ++s) \
    dst[nf][s] = *(const bf16x8*)(ldsb + (c) * 65536 + 32768 + (bbyte[nh][nf] ^ (s * 64))); \
} while (0)

// stage one 16KB unit (2 x global_load_lds / thread), inverse-swizzled source
#define STAGE_A(c, u, kt) do { \
  _Pragma("unroll") for (int i = 0; i < 2; ++i) \
    gl_lds16(Ab + aoff[i] + ((u) ? K64r : 0) + (size_t)(kt) * 64, \
             (u16*)(ldsb + (c) * 65536 + (u) * 16384 + pb[i])); \
} while (0)

#define STAGE_B(c, u, kt) do { \
  _Pragma("unroll") for (int i = 0; i < 2; ++i) \
    gl_lds16(Wb + boff[i] + ((u) ? K32r : 0) + (size_t)(kt) * 64, \
             (u16*)(ldsb + (c) * 65536 + 32768 + (u) * 16384 + pb[i])); \
} while (0)

// one C-quadrant: 16 MFMA, setprio-wrapped (T5)
#define MFMA16(mo, no, B) do { \
  __builtin_amdgcn_s_setprio(1); \
  _Pragma("unroll") for (int s = 0; s < 2; ++s) \
  _Pragma("unroll") for (int mf = 0; mf < 4; ++mf) \
  _Pragma("unroll") for (int nf = 0; nf < 2; ++nf) \
    acc[(mo) + mf][(no) + nf] = __builtin_amdgcn_mfma_f32_16x16x32_bf16( \
        a_[mf][s], B[nf][s], acc[(mo) + mf][(no) + nf], 0, 0, 0); \
  __builtin_amdgcn_s_setprio(0); \
} while (0)

template <int MODE>
__global__ __launch_bounds__(512, 2) void gemm256(const u16* __restrict__ A,
                                                  const u16* __restrict__ W, int K,
                                                  void* __restrict__ o0,
                                                  void* __restrict__ o1,
                                                  void* __restrict__ o2,
                                                  const float* __restrict__ bias,
                                                  const float* __restrict__ resid) {
  __shared__ __align__(16) u16 lds_[65536];  // 128 KiB: 2 bufs x (A 32K + B 32K)
  char* ldsb = (char*)lds_;
  const int t = threadIdx.x;
  const int l = t & 63, w = t >> 6;
  const int wm = w >> 2, wn = w & 3;            // 2 x 4 wave grid
  const int fr = l & 15, qq = l >> 4;           // 16x16 frag: row=fr, k-octet=qq

  // XCD mapping: XCD x (= wg%8) owns mt-band x*8..x*8+7, nt-major order.
  // nmt = 16384/256 = 64 for every GEMM here; nwg % 8 == 0 always.
  const int wg = blockIdx.x;
  const int xcd = wg & 7, k_ = wg >> 3;
  const int mt = xcd * 8 + (k_ & 7);
  const int nt = k_ >> 3;
  const int m0 = mt * 256, n0 = nt * 256;

  const u16* Ab = A + (size_t)m0 * K;
  const u16* Wb = W + (size_t)n0 * K;
  const size_t K64r = (size_t)K * 64;           // 64 A-rows
  const size_t K32r = (size_t)K * 32;           // 32 B-rows

  // --- staging precompute: linear LDS dest p, inverse-swizzled source ---
  // physical byte p holds logical q = p ^ (((p>>7)&7)<<4)  (3-bit slot XOR;
  // involution: bits 4-6 modified, selector bits 7-9 untouched).
  // A unit u: row R = u*64 + (prow>>6)*128 + (prow&63)
  // B unit u: row R = (prow>>5)*64 + u*32 + (prow&31)
  size_t aoff[2], boff[2];
  int pb[2];
#pragma unroll
  for (int i = 0; i < 2; ++i) {
    int p = (i * 512 + t) * 16;
    int q = p ^ (((p >> 7) & 7) << 4);
    int prow = p >> 7;                 // row bits unchanged by swizzle
    int kc = (q & 127) >> 1;
    pb[i] = p;
    aoff[i] = (size_t)(((prow >> 6) & 1) * 128 + (prow & 63)) * K + kc;
    boff[i] = (size_t)(((prow >> 5) & 3) * 64 + (prow & 31)) * K + kc;
  }
  // --- read-address precompute: slot' = (qq + 4s) ^ (slot&7) =>
  //     byte(s) = slot*128 + ((qq^(slot&3))<<4) + (((slot>>2)&1)<<6) ^ (s<<6)
  int abyte[2][4], bbyte[2][2];
#pragma unroll
  for (int mh = 0; mh < 2; ++mh)
#pragma unroll
    for (int mf = 0; mf < 4; ++mf) {
      int R = wm * 128 + (mh * 4 + mf) * 16 + fr;
      int slot = ((R >> 6) & 1) * 128 + ((R >> 7) & 1) * 64 + (R & 63);
      abyte[mh][mf] = slot * 128 + ((qq ^ (slot & 3)) << 4) + (((slot >> 2) & 1) << 6);
    }
#pragma unroll
  for (int nh = 0; nh < 2; ++nh)
#pragma unroll
    for (int nf = 0; nf < 2; ++nf) {
      int R = wn * 64 + (nh * 2 + nf) * 16 + fr;
      int slot = ((R >> 5) & 1) * 128 + ((R >> 6) & 3) * 32 + (R & 31);
      bbyte[nh][nf] = slot * 128 + ((qq ^ (slot & 3)) << 4) + (((slot >> 2) & 1) << 6);
    }

  f32x4 acc[8][4] = {};
  bf16x8 a_[4][2], b0_[2][2], b1_[2][2];

  const int nkt = K >> 6;        // K-tiles of 64
  const int niter = nkt >> 1;    // 2 K-tiles per iteration

  // prologue: tile0 complete + tile1 {Am0,Bn0,Bn1}; Am1(1) staged at P1 below
  STAGE_A(0, 0, 0); STAGE_B(0, 0, 0); STAGE_B(0, 1, 0); STAGE_A(0, 1, 0);
  STAGE_A(1, 0, 1); STAGE_B(1, 0, 1); STAGE_B(1, 1, 1);
  WAITV(6);
  BARRIER();

  for (int it = 0; it < niter - 1; ++it) {
    const int t0 = 2 * it;
    // P1: quad(m0,n0) of t0
    LDA(0, 0); LDB(0, 0, b0_);
    STAGE_A(1, 1, t0 + 1);
    BARRIER(); MFMA16(0, 0, b0_); BARRIER();
    // P2: quad(m0,n1)
    LDB(0, 1, b1_);
    STAGE_A(0, 0, t0 + 2);
    BARRIER(); MFMA16(0, 2, b1_); BARRIER();
    // P3: quad(m1,n1)
    LDA(0, 1);
    STAGE_B(0, 0, t0 + 2);
    BARRIER(); MFMA16(4, 2, b1_); BARRIER();
    // P4: quad(m1,n0) -- b0_ retained from P1
    STAGE_B(0, 1, t0 + 2);
    WAITV(6);
    BARRIER(); MFMA16(4, 0, b0_); BARRIER();
    // P5: quad(m0,n0) of t0+1
    LDA(1, 0); LDB(1, 0, b0_);
    STAGE_A(0, 1, t0 + 2);
    BARRIER(); MFMA16(0, 0, b0_); BARRIER();
    // P6: quad(m0,n1)
    LDB(1, 1, b1_);
    STAGE_A(1, 0, t0 + 3);
    BARRIER(); MFMA16(0, 2, b1_); BARRIER();
    // P7: quad(m1,n1)
    LDA(1, 1);
    STAGE_B(1, 0, t0 + 3);
    BARRIER(); MFMA16(4, 2, b1_); BARRIER();
    // P8: quad(m1,n0)
    STAGE_B(1, 1, t0 + 3);
    WAITV(6);
    BARRIER(); MFMA16(4, 0, b0_); BARRIER();
  }
  // peeled last iteration (tiles nkt-2, nkt-1); only Am1(nkt-1) left to stage
  {
    LDA(0, 0); LDB(0, 0, b0_);
    STAGE_A(1, 1, nkt - 1);
    BARRIER(); MFMA16(0, 0, b0_); BARRIER();
    LDB(0, 1, b1_);
    BARRIER(); MFMA16(0, 2, b1_); BARRIER();
    LDA(0, 1);
    BARRIER(); MFMA16(4, 2, b1_); BARRIER();
    WAITV(0);
    BARRIER(); MFMA16(4, 0, b0_); BARRIER();
    LDA(1, 0); LDB(1, 0, b0_);
    BARRIER(); MFMA16(0, 0, b0_); BARRIER();
    LDB(1, 1, b1_);
    BARRIER(); MFMA16(0, 2, b1_); BARRIER();
    LDA(1, 1);
    BARRIER(); MFMA16(4, 2, b1_); BARRIER();
    MFMA16(4, 0, b0_);
  }

  // epilogue: D element col = lane&15, row = qq*4 + r (r = 4 consecutive rows)
#pragma unroll
  for (int mi = 0; mi < 8; ++mi) {
#pragma unroll
    for (int nj = 0; nj < 4; ++nj) {
      int go = n0 + wn * 64 + nj * 16 + fr;
      int gmb = m0 + wm * 128 + mi * 16 + qq * 4;  // +r, r=0..3 consecutive
      if constexpr (MODE == M_QKV) {
        int sect = go >> 10, c = go & 1023;
        int h = c >> 6, dd = c & 63;
        int b = gmb >> 12, n = gmb & 4095;         // 4-runs stay in-batch
        int bh = b * NHEAD + h;
        if (sect == 0) {            // q = elu(v)+1, layout [bh][n][d]
#pragma unroll
          for (int r = 0; r < 4; ++r) {
            float v = acc[mi][nj][r];
            float qv = v > 0.f ? v + 1.f : __expf(v);
            ((u16*)o0)[((size_t)bh * SEQ + n + r) * HD + dd] = f2bf(qv);
          }
        } else {                    // k/v transposed [bh][d][n]: 8B vector
          u16x4 pk;
#pragma unroll
          for (int r = 0; r < 4; ++r) {
            float v = acc[mi][nj][r];
            float e = (sect == 1) ? (v > 0.f ? v + 1.f : __expf(v)) : v;
            pk[r] = f2bf(e);
          }
          u16* dst = (sect == 1) ? (u16*)o1 : (u16*)o2;
          *(u16x4*)(dst + ((size_t)bh * HD + dd) * SEQ + n) = pk;
        }
      } else {
#pragma unroll
        for (int r = 0; r < 4; ++r) {
          int gm = gmb + r;
          float v = acc[mi][nj][r];
          if constexpr (MODE == M_PROJ) {
            ((float*)o0)[(size_t)gm * CDIM + go] = v + bias[go] + resid[(size_t)gm * CDIM + go];
          } else if constexpr (MODE == M_FC1) {
            float u = v + bias[go];
            ((u16*)o0)[(size_t)gm * HID + go] = f2bf(gelu_fast(u));
          } else {  // M_FC2
            ((float*)o0)[(size_t)gm * CDIM + go] = v + bias[go] + resid[(size_t)gm * CDIM + go];
          }
        }
      }
    }
  }
}

// ------- kv state: partial kvT[e][d] = sum_n v[n,e]*k[n,d], per n-chunk -----
__global__ __launch_bounds__(256) void kv_stage1(const u16* __restrict__ kt,
                                                 const u16* __restrict__ vt,
                                                 float* __restrict__ pkv,
                                                 float* __restrict__ pks) {
  int ch = blockIdx.x, bh = blockIdx.y;
  int t = threadIdx.x, l = t & 63, w = t >> 6;
  int fr = l & 15, qq = l >> 4;
  int nb = ch * 512;
  const u16* vb = vt + (size_t)bh * HD * SEQ;
  const u16* kb = kt + (size_t)bh * HD * SEQ;
  int e0 = (w >> 1) * 32, d0 = (w & 1) * 32;
  f32x4 acc[2][2] = {};
  for (int kk = 0; kk < 512; kk += 32) {
    bf16x8 af[2], bfv[2];
#pragma unroll
    for (int i = 0; i < 2; ++i)
      af[i] = *(const bf16x8*)(vb + (size_t)(e0 + i * 16 + fr) * SEQ + nb + kk + qq * 8);
#pragma unroll
    for (int j = 0; j < 2; ++j)
      bfv[j] = *(const bf16x8*)(kb + (size_t)(d0 + j * 16 + fr) * SEQ + nb + kk + qq * 8);
#pragma unroll
    for (int i = 0; i < 2; ++i)
#pragma unroll
      for (int j = 0; j < 2; ++j)
        acc[i][j] = __builtin_amdgcn_mfma_f32_16x16x32_bf16(af[i], bfv[j], acc[i][j], 0, 0, 0);
  }
  float* pout = pkv + ((size_t)ch * NBH + bh) * 4096;
#pragma unroll
  for (int i = 0; i < 2; ++i)
#pragma unroll
    for (int j = 0; j < 2; ++j)
#pragma unroll
      for (int r = 0; r < 4; ++r) {
        int e = e0 + i * 16 + qq * 4 + r;
        int d = d0 + j * 16 + fr;
        pout[e * 64 + d] = acc[i][j][r];
      }
  // partial ksum over this n-chunk
  __shared__ float ksp[256];
  {
    int d = t & 63, part = t >> 6;
    const u16* kr = kb + (size_t)d * SEQ + nb + part * 128;
    float s = 0;
    for (int n = 0; n < 128; ++n) s += bf2f(kr[n]);
    ksp[t] = s;
  }
  __syncthreads();
  if (t < 64) {
    float s = ksp[t] + ksp[64 + t] + ksp[128 + t] + ksp[192 + t];
    pks[((size_t)ch * NBH + bh) * 64 + t] = s;
  }
}

__global__ __launch_bounds__(256) void kv_reduce(const float* __restrict__ pkv,
                                                 const float* __restrict__ pks,
                                                 u16* __restrict__ kvt,
                                                 float* __restrict__ ksm) {
  int bh = blockIdx.x, t = threadIdx.x;
  for (int ii = 0; ii < 16; ++ii) {
    int idx = ii * 256 + t;
    float s = 0;
#pragma unroll
    for (int c = 0; c < 8; ++c) s += pkv[((size_t)c * NBH + bh) * 4096 + idx];
    kvt[(size_t)bh * 4096 + idx] = f2bf(s);
  }
  if (t < 64) {
    float s = 0;
#pragma unroll
    for (int c = 0; c < 8; ++c) s += pks[((size_t)c * NBH + bh) * 64 + t];
    ksm[bh * 64 + t] = s;
  }
}

// ------- attn: out[n,e] = (sum_d q[n,d]*kvT[e,d]) * z[n], -> [b,n,c] bf16 ---
__global__ __launch_bounds__(256) void attn_kernel(const u16* __restrict__ qb,
                                                   const u16* __restrict__ kvt,
                                                   const float* __restrict__ ksm,
                                                   u16* __restrict__ ab) {
  int nblk = blockIdx.x, bh = blockIdx.y;
  int n0 = nblk * 128;
  int t = threadIdx.x, l = t & 63, w = t >> 6;
  int fr = l & 15, qq = l >> 4;
  __shared__ float ksh[64];
  __shared__ float part[256];
  __shared__ float zsh[128];
  if (t < 64) ksh[t] = ksm[bh * 64 + t];
  __syncthreads();
  {
    int rr = t >> 1, hf = t & 1;
    const u16* qr = qb + ((size_t)bh * SEQ + n0 + rr) * HD + hf * 32;
    float s = 0;
#pragma unroll
    for (int d = 0; d < 32; ++d) s += bf2f(qr[d]) * ksh[hf * 32 + d];
    part[t] = s;
  }
  __syncthreads();
  if (t < 128) zsh[t] = 1.0f / (part[2 * t] + part[2 * t + 1] + 1e-6f);
  __syncthreads();

  f32x4 acc[2][4] = {};
  const u16* qbase = qb + ((size_t)bh * SEQ + n0) * HD;
  const u16* kvb = kvt + (size_t)bh * 4096;
#pragma unroll
  for (int ks = 0; ks < 64; ks += 32) {
    bf16x8 af[2], bfv[4];
#pragma unroll
    for (int i = 0; i < 2; ++i)
      af[i] = *(const bf16x8*)(qbase + (size_t)(w * 32 + i * 16 + fr) * HD + ks + qq * 8);
#pragma unroll
    for (int j = 0; j < 4; ++j)
      bfv[j] = *(const bf16x8*)(kvb + (size_t)(j * 16 + fr) * HD + ks + qq * 8);
#pragma unroll
    for (int i = 0; i < 2; ++i)
#pragma unroll
      for (int j = 0; j < 4; ++j)
        acc[i][j] = __builtin_amdgcn_mfma_f32_16x16x32_bf16(af[i], bfv[j], acc[i][j], 0, 0, 0);
  }
  int b = bh >> 4, h = bh & 15;
#pragma unroll
  for (int i = 0; i < 2; ++i)
#pragma unroll
    for (int j = 0; j < 4; ++j)
#pragma unroll
      for (int r = 0; r < 4; ++r) {
        int rl = w * 32 + i * 16 + qq * 4 + r;
        int n = n0 + rl;
        int e = j * 16 + fr;
        float v = acc[i][j][r] * zsh[rl];
        ab[((size_t)(b * SEQ + n)) * CDIM + h * HD + e] = f2bf(v);
      }
}

// ---------------------------------------------------------------------------
extern "C" void kernel_launch(void* const* d_in, const int* in_sizes, int n_in,
                              void* d_out, int out_size, void* d_ws, size_t ws_size,
                              hipStream_t stream) {
  (void)in_sizes; (void)n_in; (void)out_size; (void)ws_size;
  const float* x     = (const float*)d_in[0];
  const float* n1g   = (const float*)d_in[1];
  const float* n1b   = (const float*)d_in[2];
  const float* qkvw  = (const float*)d_in[3];
  const float* projw = (const float*)d_in[4];
  const float* projb = (const float*)d_in[5];
  const float* n2g   = (const float*)d_in[6];
  const float* n2b   = (const float*)d_in[7];
  const float* fc1w  = (const float*)d_in[8];
  const float* fc1b  = (const float*)d_in[9];
  const float* fc2w  = (const float*)d_in[10];
  const float* fc2b  = (const float*)d_in[11];
  float* out = (float*)d_out;

  char* ws = (char*)d_ws;
  size_t off = 0;
  auto alloc = [&](size_t bytes) {
    void* p = ws + off;
    off += (bytes + 255) & ~(size_t)255;
    return p;
  };
  // --- persistent-lifetime allocations (248.5 MiB total incl. pool) ---
  u16*  wq   = (u16*)alloc((size_t)3 * CDIM * CDIM * 2);   // 6 MB  qkv_w bf16
  u16*  wp   = (u16*)alloc((size_t)CDIM * CDIM * 2);       // 2 MB  proj_w bf16
  u16*  w1   = (u16*)alloc((size_t)HID * CDIM * 2);        // 8 MB  fc1_w bf16
  u16*  w2   = (u16*)alloc((size_t)CDIM * HID * 2);        // 8 MB  fc2_w bf16
  u16*  kvt  = (u16*)alloc((size_t)NBH * 4096 * 2);        // 512KB kvT bf16
  float* ksm = (float*)alloc((size_t)NBH * 64 * 4);        // 16 KB ksum
  float* x2  = (float*)alloc((size_t)TOK * CDIM * 4);      // 64 MB x + attn (fp32)
  u16*  h12  = (u16*)alloc((size_t)TOK * CDIM * 2);        // 32 MB ln1 out, later ln2 out
  // --- 128 MB pool with overlaid lifetimes ---
  u16*  qbuf = (u16*)alloc((size_t)TOK * CDIM * 2);        // 32 MB phi(q) [bh][n][d]
  u16*  ktb  = (u16*)alloc((size_t)TOK * CDIM * 2);        // 32 MB phi(k) [bh][d][n]
  u16*  vtb  = (u16*)alloc((size_t)TOK * CDIM * 2);        // 32 MB v      [bh][d][n]
  u16*  abuf = (u16*)alloc((size_t)TOK * CDIM * 2);        // 32 MB attn out [b,n,c]
  // pkv/pks overlay abuf: dead before attn_kernel writes abuf
  float* pkv = (float*)abuf;                               // 8 MB  partial kv
  float* pks = (float*)(abuf + (size_t)8 * NBH * 4096 * 2);// 128KB partial ksum
  u16*  h3   = qbuf;  // 128 MB gelu out: reuses qbuf..abuf (all dead after proj)

  // weights fp32 -> bf16
  cvt_kernel<<<dim3(3 * CDIM * CDIM / 1024), 256, 0, stream>>>(qkvw, wq, 3 * CDIM * CDIM / 4);
  cvt_kernel<<<dim3(CDIM * CDIM / 1024),     256, 0, stream>>>(projw, wp, CDIM * CDIM / 4);
  cvt_kernel<<<dim3(HID * CDIM / 1024),      256, 0, stream>>>(fc1w, w1, HID * CDIM / 4);
  cvt_kernel<<<dim3(CDIM * HID / 1024),      256, 0, stream>>>(fc2w, w2, CDIM * HID / 4);

  ln_kernel<<<dim3(TOK), 256, 0, stream>>>(x, n1g, n1b, h12);
  gemm256<M_QKV><<<dim3(64 * 12), 512, 0, stream>>>(
      h12, wq, CDIM, qbuf, ktb, vtb, nullptr, nullptr);
  kv_stage1<<<dim3(8, NBH), 256, 0, stream>>>(ktb, vtb, pkv, pks);
  kv_reduce<<<dim3(NBH), 256, 0, stream>>>(pkv, pks, kvt, ksm);
  attn_kernel<<<dim3(SEQ / 128, NBH), 256, 0, stream>>>(qbuf, kvt, ksm, abuf);
  gemm256<M_PROJ><<<dim3(64 * 4), 512, 0, stream>>>(
      abuf, wp, CDIM, x2, nullptr, nullptr, projb, x);
  ln_kernel<<<dim3(TOK), 256, 0, stream>>>(x2, n2g, n2b, h12);
  gemm256<M_FC1><<<dim3(64 * 16), 512, 0, stream>>>(
      h12, w1, CDIM, h3, nullptr, nullptr, fc1b, nullptr);
  gemm256<M_FC2><<<dim3(64 * 4), 512, 0, stream>>>(
      h3, w2, HID, out, nullptr, nullptr, fc2b, x2);
}